// Round 3
// baseline (156.256 us; speedup 1.0000x reference)
//
#include <hip/hip_runtime.h>
#include <hip/hip_bf16.h>
#include <cstdint>
#include <cstddef>

// ---------------------------------------------------------------------------
// out = softmax(Q K^T / 128) V, N=M=8192, d=128, fp32 in/out.
// Round 3: 32x32x16 bf16 MFMA; K fragments read DIRECT from global (Kbc is
// fragment-contiguous, L1/L2-resident per split); V double-buffered in LDS
// (one barrier/iter); P C->A layout transform via shfl_xor(32) half-exchange
// (no LDS round trip). NSPLIT=16 (ws-gated to 8) -> 4 blocks/CU.
// ---------------------------------------------------------------------------

typedef __attribute__((ext_vector_type(8))) short short8;     // 8 bf16
typedef __attribute__((ext_vector_type(4))) short shortx4;    // 4 bf16
typedef __attribute__((ext_vector_type(4))) float floatx4;
typedef __attribute__((ext_vector_type(16))) float floatx16;
typedef __attribute__((ext_vector_type(8))) _Float16 half8;

#define N_Q    8192
#define N_KV   8192
#define DHEAD  128
#define BK     64
// fold 1/128 scaling and log2(e) into Q: scores in exp2 domain
#define QSCALE (1.4426950408889634f / 128.0f)

static __device__ __forceinline__ unsigned short f2bf(float x) {
  __hip_bfloat16 h = __float2bfloat16(x);
  unsigned short u;
  __builtin_memcpy(&u, &h, 2);
  return u;
}

static __device__ __forceinline__ uint32_t pack_bf2(float a, float b) {
  return (uint32_t)f2bf(a) | ((uint32_t)f2bf(b) << 16);
}

#define MFMA32(a, b, c) __builtin_amdgcn_mfma_f32_32x32x16_bf16((a), (b), (c), 0, 0, 0)

#define GLD_LDS16(g, l)                                                        \
  __builtin_amdgcn_global_load_lds(                                            \
      (const __attribute__((address_space(1))) void*)(g),                      \
      (__attribute__((address_space(3))) void*)(l), 16, 0, 0)

// ---------------------------------------------------------------------------
// Fused convert kernel (unchanged from round 2).
// Blocks [0,512):   K[8192][128] f32 -> Kbc chunk-major bf16:
//   ((b*16 + ch)*64 + ki)*8 + j == bf16(K[b*64+ki][ch*8+j])
// Blocks [512,1536): V[8192][128] f32 -> Vtc transposed chunk-major bf16:
//   ((b*8 + c2)*128 + dv)*8 + kk == bf16(V[b*64 + c2*8 + kk][dv])
// ---------------------------------------------------------------------------
__global__ void cvt_kernel(const float* __restrict__ K,
                           const float* __restrict__ V,
                           unsigned short* __restrict__ Kbc,
                           unsigned short* __restrict__ Vtc) {
  int bid = blockIdx.x;
  if (bid < 512) {
    int tid = bid * 256 + threadIdx.x;
    int ki = tid & 63;
    int ch = (tid >> 6) & 15;
    int b  = tid >> 10;
    const float* src = K + ((size_t)(b * 64 + ki) * DHEAD + ch * 8);
    floatx4 f0 = *(const floatx4*)src;
    floatx4 f1 = *(const floatx4*)(src + 4);
    short8 o;
    o[0] = (short)f2bf(f0[0]); o[1] = (short)f2bf(f0[1]);
    o[2] = (short)f2bf(f0[2]); o[3] = (short)f2bf(f0[3]);
    o[4] = (short)f2bf(f1[0]); o[5] = (short)f2bf(f1[1]);
    o[6] = (short)f2bf(f1[2]); o[7] = (short)f2bf(f1[3]);
    *(short8*)(Kbc + (size_t)tid * 8) = o;
  } else {
    int tid = (bid - 512) * 256 + threadIdx.x;
    int kh = tid & 1;
    int dv = (tid >> 1) & 127;
    int c2 = (tid >> 8) & 7;
    int b  = tid >> 11;
    int k0 = b * 64 + c2 * 8 + kh * 4;
    shortx4 o;
    o[0] = (short)f2bf(V[(size_t)(k0 + 0) * DHEAD + dv]);
    o[1] = (short)f2bf(V[(size_t)(k0 + 1) * DHEAD + dv]);
    o[2] = (short)f2bf(V[(size_t)(k0 + 2) * DHEAD + dv]);
    o[3] = (short)f2bf(V[(size_t)(k0 + 3) * DHEAD + dv]);
    *(shortx4*)(Vtc + (size_t)tid * 4) = o;
  }
}

// ---------------------------------------------------------------------------
// Flash attention. Block = 256 threads (4 waves); wave w owns queries
// [blockIdx.x*128 + w*32, +32); split sp = blockIdx.y owns keys
// [sp*(8192/nsp), ...) in NT = 128/nsp tiles of 64.
// S^T = K.Q^T with K frags straight from global; p = exp2(s); P C-layout ->
// A-frags via shfl_xor(32) exchange; O += P.V from double-buffered LDS V.
// ---------------------------------------------------------------------------
__global__ __launch_bounds__(256, 3) void attn_kernel(
    const float* __restrict__ Q, const unsigned short* __restrict__ Kbc,
    const unsigned short* __restrict__ Vtc, _Float16* __restrict__ Opart,
    float* __restrict__ Lst) {
  __shared__ unsigned short Vts[2][8192];  // 2 x 16KB double buffer

  const int t = threadIdx.x;
  const int w = t >> 6;
  const int lane = t & 63;
  const int h = lane >> 5;  // half 0/1
  const int c = lane & 31;  // 0..31
  const int qbase = blockIdx.x * 128 + w * 32;
  const int sp = blockIdx.y;
  const int nsp = gridDim.y;
  const int NT = (N_KV / BK) / nsp;  // 8 (nsp=16) or 16 (nsp=8)
  const int kb0 = sp * NT;

  // Q B-frags: B[k=d][n=q]; lane: n = c (query), k = (h*8 + j) within chunk.
  short8 qf[8];
  {
    const float* qrow = Q + (size_t)(qbase + c) * DHEAD + h * 8;
#pragma unroll
    for (int dc = 0; dc < 8; ++dc) {
      floatx4 f0 = *(const floatx4*)(qrow + dc * 16);
      floatx4 f1 = *(const floatx4*)(qrow + dc * 16 + 4);
      short8 s;
      s[0] = (short)f2bf(f0[0] * QSCALE); s[1] = (short)f2bf(f0[1] * QSCALE);
      s[2] = (short)f2bf(f0[2] * QSCALE); s[3] = (short)f2bf(f0[3] * QSCALE);
      s[4] = (short)f2bf(f1[0] * QSCALE); s[5] = (short)f2bf(f1[1] * QSCALE);
      s[6] = (short)f2bf(f1[2] * QSCALE); s[7] = (short)f2bf(f1[3] * QSCALE);
      qf[dc] = s;
    }
  }

  // O accum: acc[nb]: col dv = nb*32 + c, row q = (r&3)+8*(r>>2)+4*h
  floatx16 acc[4];
#pragma unroll
  for (int i = 0; i < 4; ++i)
#pragma unroll
    for (int r = 0; r < 16; ++r) acc[i][r] = 0.f;
  float lsum = 0.f;

  // stage V tile 0 (16KB = 16 slabs of 1KB; 4 slabs per wave)
  {
    const unsigned short* vg = Vtc + (size_t)kb0 * 8192;
#pragma unroll
    for (int i = 0; i < 4; ++i) {
      int slab = w * 4 + i;  // wave-uniform
      GLD_LDS16(vg + slab * 512 + lane * 8, &Vts[0][0] + slab * 512);
    }
  }
  __syncthreads();

  for (int it = 0; it < NT; ++it) {
    const int kb = kb0 + it;
    // prefetch next V tile into the other buffer (overlaps with compute;
    // drained by the barrier at loop end)
    if (it + 1 < NT) {
      const unsigned short* vg = Vtc + (size_t)(kb + 1) * 8192;
      unsigned short* dst = &Vts[(it + 1) & 1][0];
#pragma unroll
      for (int i = 0; i < 4; ++i) {
        int slab = w * 4 + i;
        GLD_LDS16(vg + slab * 512 + lane * 8, dst + slab * 512);
      }
    }

    const short8* Kg = (const short8*)(Kbc + (size_t)kb * 8192);
    const short8* VtsF = (const short8*)&Vts[it & 1][0];

#pragma unroll
    for (int st = 0; st < 2; ++st) {
      // ---- S^T = K.Q^T for keys st*32..+31 (K frags from global) ----
      floatx16 sc;
#pragma unroll
      for (int r = 0; r < 16; ++r) sc[r] = 0.f;
#pragma unroll
      for (int dc = 0; dc < 8; ++dc) {
        short8 a = Kg[(dc * 2 + h) * 64 + st * 32 + c];  // key = st*32+c
        sc = MFMA32(a, qf[dc], sc);
      }
      // lane holds col q=c, row key_rel = (r&3)+8*(r>>2)+4h (+st*32).
      // quad r2 (=r>>2) covers keys 8*r2+4h+{0..3}.
      uint32_t qd[8];  // [r2][dw]
#pragma unroll
      for (int r2 = 0; r2 < 4; ++r2) {
        float p0 = exp2f(sc[r2 * 4 + 0]);
        float p1 = exp2f(sc[r2 * 4 + 1]);
        float p2 = exp2f(sc[r2 * 4 + 2]);
        float p3 = exp2f(sc[r2 * 4 + 3]);
        lsum += (p0 + p1) + (p2 + p3);
        qd[r2 * 2 + 0] = pack_bf2(p0, p1);
        qd[r2 * 2 + 1] = pack_bf2(p2, p3);
      }
      // ---- C->A transform: chunk kc=st*2+b needs quad r2*=2b+h from both
      // halves; send quad 2b+(h^1), receive partner's quad 2b+h. ----
#pragma unroll
      for (int b = 0; b < 2; ++b) {
        uint32_t s0 = h ? qd[(2 * b) * 2 + 0] : qd[(2 * b + 1) * 2 + 0];
        uint32_t s1 = h ? qd[(2 * b) * 2 + 1] : qd[(2 * b + 1) * 2 + 1];
        uint32_t r0 = __shfl_xor(s0, 32, 64);
        uint32_t r1 = __shfl_xor(s1, 32, 64);
        uint32_t o0 = h ? qd[(2 * b + 1) * 2 + 0] : qd[(2 * b) * 2 + 0];
        uint32_t o1 = h ? qd[(2 * b + 1) * 2 + 1] : qd[(2 * b) * 2 + 1];
        uint32_t f[4];
        f[0] = h ? r0 : o0;  // keys h*8+0..1, +2..3 (slot h'=0)
        f[1] = h ? r1 : o1;
        f[2] = h ? o0 : r0;  // keys h*8+4..7 (slot h'=1)
        f[3] = h ? o1 : r1;
        short8 pf;
        __builtin_memcpy(&pf, f, 16);
        const int kc = st * 2 + b;
        // ---- O += P.V for this 16-key chunk ----
#pragma unroll
        for (int nb = 0; nb < 4; ++nb) {
          short8 bv = VtsF[(kc * 2 + h) * 128 + nb * 32 + c];
          acc[nb] = MFMA32(pf, bv, acc[nb]);
        }
      }
    }
    __syncthreads();  // all waves done with buf[it&1]; next stage drained
  }

  // ---- epilogue ----
  lsum += __shfl_xor(lsum, 32, 64);
  if (h == 0) Lst[(size_t)sp * N_Q + qbase + c] = lsum;
  _Float16* op = Opart + ((size_t)sp * N_Q + qbase) * DHEAD;
#pragma unroll
  for (int nb = 0; nb < 4; ++nb)
#pragma unroll
    for (int r = 0; r < 16; ++r) {
      int row = (r & 3) + 8 * (r >> 2) + 4 * h;
      op[(size_t)row * DHEAD + nb * 32 + c] = (_Float16)acc[nb][r];
    }
}

// ---------------------------------------------------------------------------
// Merge: out[g][dv] = sum_s O_s[g][dv] / sum_s l_s[g].
// ---------------------------------------------------------------------------
__global__ void merge_kernel(const _Float16* __restrict__ Opart,
                             const float* __restrict__ Lst,
                             float* __restrict__ out, int nsp) {
  int tid = blockIdx.x * blockDim.x + threadIdx.x;
  int g = tid >> 4;
  int d0 = (tid & 15) * 8;
  float den = 0.f;
  float num[8] = {0.f, 0.f, 0.f, 0.f, 0.f, 0.f, 0.f, 0.f};
  for (int s = 0; s < nsp; ++s) {
    den += Lst[(size_t)s * N_Q + g];
    half8 o = *(const half8*)(Opart + ((size_t)s * N_Q + g) * DHEAD + d0);
#pragma unroll
    for (int j = 0; j < 8; ++j) num[j] += (float)o[j];
  }
  float inv = 1.0f / den;
  floatx4 r0 = (floatx4){num[0] * inv, num[1] * inv, num[2] * inv, num[3] * inv};
  floatx4 r1 = (floatx4){num[4] * inv, num[5] * inv, num[6] * inv, num[7] * inv};
  float* dst = out + (size_t)g * DHEAD + d0;
  *(floatx4*)dst = r0;
  *(floatx4*)(dst + 4) = r1;
}

// ---------------------------------------------------------------------------
extern "C" void kernel_launch(void* const* d_in, const int* in_sizes, int n_in,
                              void* d_out, int out_size, void* d_ws,
                              size_t ws_size, hipStream_t stream) {
  const float* Q = (const float*)d_in[0];
  const float* K = (const float*)d_in[1];
  const float* V = (const float*)d_in[2];
  float* out = (float*)d_out;

  // ws layout: Kbc 2MiB | Vtc 2MiB | Opart fp16 nsp*2MiB | Lst nsp*32KiB
  const size_t need16 = (4ull << 20) + 16ull * N_Q * DHEAD * 2 + 16ull * N_Q * 4;
  const int nsp = (ws_size >= need16) ? 16 : 8;

  char* ws = (char*)d_ws;
  unsigned short* Kbc = (unsigned short*)(ws);
  unsigned short* Vtc = (unsigned short*)(ws + (2u << 20));
  _Float16* Opart = (_Float16*)(ws + (4u << 20));
  float* Lst = (float*)(ws + (4ull << 20) + (size_t)nsp * N_Q * DHEAD * 2);

  cvt_kernel<<<dim3(1536), dim3(256), 0, stream>>>(K, V, Kbc, Vtc);
  attn_kernel<<<dim3(N_Q / 128, nsp), dim3(256), 0, stream>>>(Q, Kbc, Vtc,
                                                              Opart, Lst);
  merge_kernel<<<dim3(512), dim3(256), 0, stream>>>(Opart, Lst, out, nsp);
}

// Round 4
// 121.664 us; speedup vs baseline: 1.2843x; 1.2843x over previous
//
#include <hip/hip_runtime.h>
#include <hip/hip_bf16.h>
#include <cstdint>
#include <cstddef>

// ---------------------------------------------------------------------------
// out = softmax(Q K^T / 128) V, N=M=8192, d=128, fp32 in/out.
// Round 4: R2 structure (K+V staged in LDS via global_load_lds width=16) +
// R3's verified shfl_xor(32) C->A transform for P (no P LDS round-trip,
// 32KB LDS/block) + truncation bf16 pack for P (normalization cancels the
// bias) + hoisted staging addressing. nsp=16, 3 blocks/CU.
// ---------------------------------------------------------------------------

typedef __attribute__((ext_vector_type(8))) short short8;     // 8 bf16
typedef __attribute__((ext_vector_type(4))) short shortx4;    // 4 bf16
typedef __attribute__((ext_vector_type(4))) float floatx4;
typedef __attribute__((ext_vector_type(16))) float floatx16;
typedef __attribute__((ext_vector_type(8))) _Float16 half8;

#define N_Q    8192
#define N_KV   8192
#define DHEAD  128
#define BK     64
// fold 1/128 scaling and log2(e) into Q: scores in exp2 domain
#define QSCALE (1.4426950408889634f / 128.0f)

static __device__ __forceinline__ unsigned short f2bf(float x) {
  __hip_bfloat16 h = __float2bfloat16(x);
  unsigned short u;
  __builtin_memcpy(&u, &h, 2);
  return u;
}

// truncating bf16x2 pack: softmax normalization cancels the common downward
// bias; residual jitter ~1e-4 absmax, well inside threshold. 3 VALU ops.
static __device__ __forceinline__ uint32_t trunc_pack(float a, float b) {
  uint32_t ua, ub;
  __builtin_memcpy(&ua, &a, 4);
  __builtin_memcpy(&ub, &b, 4);
  return (ua >> 16) | (ub & 0xffff0000u);
}

#define MFMA32(a, b, c) __builtin_amdgcn_mfma_f32_32x32x16_bf16((a), (b), (c), 0, 0, 0)

#define GLD_LDS16(g, l)                                                        \
  __builtin_amdgcn_global_load_lds(                                            \
      (const __attribute__((address_space(1))) void*)(g),                      \
      (__attribute__((address_space(3))) void*)(l), 16, 0, 0)

// ---------------------------------------------------------------------------
// Fused convert kernel (unchanged).
// Blocks [0,512):   K[8192][128] f32 -> Kbc chunk-major bf16:
//   ((b*16 + ch)*64 + ki)*8 + j == bf16(K[b*64+ki][ch*8+j])
// Blocks [512,1536): V[8192][128] f32 -> Vtc transposed chunk-major bf16:
//   ((b*8 + c2)*128 + dv)*8 + kk == bf16(V[b*64 + c2*8 + kk][dv])
// ---------------------------------------------------------------------------
__global__ void cvt_kernel(const float* __restrict__ K,
                           const float* __restrict__ V,
                           unsigned short* __restrict__ Kbc,
                           unsigned short* __restrict__ Vtc) {
  int bid = blockIdx.x;
  if (bid < 512) {
    int tid = bid * 256 + threadIdx.x;
    int ki = tid & 63;
    int ch = (tid >> 6) & 15;
    int b  = tid >> 10;
    const float* src = K + ((size_t)(b * 64 + ki) * DHEAD + ch * 8);
    floatx4 f0 = *(const floatx4*)src;
    floatx4 f1 = *(const floatx4*)(src + 4);
    short8 o;
    o[0] = (short)f2bf(f0[0]); o[1] = (short)f2bf(f0[1]);
    o[2] = (short)f2bf(f0[2]); o[3] = (short)f2bf(f0[3]);
    o[4] = (short)f2bf(f1[0]); o[5] = (short)f2bf(f1[1]);
    o[6] = (short)f2bf(f1[2]); o[7] = (short)f2bf(f1[3]);
    *(short8*)(Kbc + (size_t)tid * 8) = o;
  } else {
    int tid = (bid - 512) * 256 + threadIdx.x;
    int kh = tid & 1;
    int dv = (tid >> 1) & 127;
    int c2 = (tid >> 8) & 7;
    int b  = tid >> 11;
    int k0 = b * 64 + c2 * 8 + kh * 4;
    shortx4 o;
    o[0] = (short)f2bf(V[(size_t)(k0 + 0) * DHEAD + dv]);
    o[1] = (short)f2bf(V[(size_t)(k0 + 1) * DHEAD + dv]);
    o[2] = (short)f2bf(V[(size_t)(k0 + 2) * DHEAD + dv]);
    o[3] = (short)f2bf(V[(size_t)(k0 + 3) * DHEAD + dv]);
    *(shortx4*)(Vtc + (size_t)tid * 4) = o;
  }
}

// ---------------------------------------------------------------------------
// Flash attention. Block = 256 threads (4 waves); wave w owns queries
// [blockIdx.x*128 + w*32, +32); split sp = blockIdx.y owns keys
// [sp*(8192/nsp), ...) in NT tiles of 64. Per tile: stage K+V to LDS,
// S^T = K.Q^T (LDS K frags), p = exp2(s) + truncation pack, C->A via
// shfl_xor(32), O += P.V (LDS V frags).
// ---------------------------------------------------------------------------
__global__ __launch_bounds__(256, 3) void attn_kernel(
    const float* __restrict__ Q, const unsigned short* __restrict__ Kbc,
    const unsigned short* __restrict__ Vtc, _Float16* __restrict__ Opart,
    float* __restrict__ Lst) {
  __shared__ unsigned short Ks[8192];   // 16KB: [16 chunks][64 keys][8 bf16]
  __shared__ unsigned short Vts[8192];  // 16KB: [8 kchunks][128 dv][8 bf16]

  const int t = threadIdx.x;
  const int w = t >> 6;
  const int lane = t & 63;
  const int h = lane >> 5;  // half 0/1
  const int c = lane & 31;  // 0..31
  const int qbase = blockIdx.x * 128 + w * 32;
  const int sp = blockIdx.y;
  const int nsp = gridDim.y;
  const int NT = (N_KV / BK) / nsp;  // 8 at nsp=16
  const int kb0 = sp * NT;

  // Q B-frags: B[k=d][n=q]; lane: n = c (query), k = (h*8 + j) within chunk.
  short8 qf[8];
  {
    const float* qrow = Q + (size_t)(qbase + c) * DHEAD + h * 8;
#pragma unroll
    for (int dc = 0; dc < 8; ++dc) {
      floatx4 f0 = *(const floatx4*)(qrow + dc * 16);
      floatx4 f1 = *(const floatx4*)(qrow + dc * 16 + 4);
      short8 s;
      s[0] = (short)f2bf(f0[0] * QSCALE); s[1] = (short)f2bf(f0[1] * QSCALE);
      s[2] = (short)f2bf(f0[2] * QSCALE); s[3] = (short)f2bf(f0[3] * QSCALE);
      s[4] = (short)f2bf(f1[0] * QSCALE); s[5] = (short)f2bf(f1[1] * QSCALE);
      s[6] = (short)f2bf(f1[2] * QSCALE); s[7] = (short)f2bf(f1[3] * QSCALE);
      qf[dc] = s;
    }
  }

  // O accum: acc[nb]: col dv = nb*32 + c, row q = (r&3)+8*(r>>2)+4*h
  floatx16 acc[4];
#pragma unroll
  for (int i = 0; i < 4; ++i)
#pragma unroll
    for (int r = 0; r < 16; ++r) acc[i][r] = 0.f;
  float lsum = 0.f;

  // hoisted staging pointers: wave w stages slabs w*4..w*4+3 of each tile
  const unsigned short* kp = Kbc + (size_t)kb0 * 8192 + (w * 4) * 512 + lane * 8;
  const unsigned short* vp = Vtc + (size_t)kb0 * 8192 + (w * 4) * 512 + lane * 8;
  unsigned short* kdst = Ks + (w * 4) * 512;   // wave-uniform LDS base
  unsigned short* vdst = Vts + (w * 4) * 512;

  for (int it = 0; it < NT; ++it) {
#pragma unroll
    for (int i = 0; i < 4; ++i) {
      GLD_LDS16(kp + i * 512, kdst + i * 512);
      GLD_LDS16(vp + i * 512, vdst + i * 512);
    }
    kp += 8192;
    vp += 8192;
    __syncthreads();  // staging drained (vmcnt) + all waves ready

    const short8* KsF = (const short8*)Ks;
    const short8* VtsF = (const short8*)Vts;

#pragma unroll
    for (int st = 0; st < 2; ++st) {
      // ---- S^T = K.Q^T for keys st*32..+31 ----
      floatx16 sc;
#pragma unroll
      for (int r = 0; r < 16; ++r) sc[r] = 0.f;
#pragma unroll
      for (int dc = 0; dc < 8; ++dc) {
        short8 a = KsF[(dc * 2 + h) * 64 + st * 32 + c];  // key = st*32+c
        sc = MFMA32(a, qf[dc], sc);
      }
      // lane holds col q=c, row key_rel = (r&3)+8*(r>>2)+4h (+st*32);
      // quad r2 covers keys 8*r2+4h+{0..3}.
      uint32_t qd[8];
#pragma unroll
      for (int r2 = 0; r2 < 4; ++r2) {
        float p0 = exp2f(sc[r2 * 4 + 0]);
        float p1 = exp2f(sc[r2 * 4 + 1]);
        float p2 = exp2f(sc[r2 * 4 + 2]);
        float p3 = exp2f(sc[r2 * 4 + 3]);
        lsum += (p0 + p1) + (p2 + p3);
        qd[r2 * 2 + 0] = trunc_pack(p0, p1);
        qd[r2 * 2 + 1] = trunc_pack(p2, p3);
      }
      // ---- C->A transform (verified R3): chunk kc=st*2+b needs quad 2b+h
      // from both halves; exchange the partner's via shfl_xor(32). ----
#pragma unroll
      for (int b = 0; b < 2; ++b) {
        uint32_t s0 = h ? qd[(2 * b) * 2 + 0] : qd[(2 * b + 1) * 2 + 0];
        uint32_t s1 = h ? qd[(2 * b) * 2 + 1] : qd[(2 * b + 1) * 2 + 1];
        uint32_t r0 = __shfl_xor(s0, 32, 64);
        uint32_t r1 = __shfl_xor(s1, 32, 64);
        uint32_t o0 = h ? qd[(2 * b + 1) * 2 + 0] : qd[(2 * b) * 2 + 0];
        uint32_t o1 = h ? qd[(2 * b + 1) * 2 + 1] : qd[(2 * b) * 2 + 1];
        uint32_t f[4];
        f[0] = h ? r0 : o0;
        f[1] = h ? r1 : o1;
        f[2] = h ? o0 : r0;
        f[3] = h ? o1 : r1;
        short8 pf;
        __builtin_memcpy(&pf, f, 16);
        const int kc = st * 2 + b;
        // ---- O += P.V for this 16-key chunk ----
#pragma unroll
        for (int nb = 0; nb < 4; ++nb) {
          short8 bv = VtsF[(kc * 2 + h) * 128 + nb * 32 + c];
          acc[nb] = MFMA32(pf, bv, acc[nb]);
        }
      }
    }
    __syncthreads();  // all waves done with Ks/Vts before restage
  }

  // ---- epilogue ----
  lsum += __shfl_xor(lsum, 32, 64);
  if (h == 0) Lst[(size_t)sp * N_Q + qbase + c] = lsum;
  _Float16* op = Opart + ((size_t)sp * N_Q + qbase) * DHEAD;
#pragma unroll
  for (int nb = 0; nb < 4; ++nb)
#pragma unroll
    for (int r = 0; r < 16; ++r) {
      int row = (r & 3) + 8 * (r >> 2) + 4 * h;
      op[(size_t)row * DHEAD + nb * 32 + c] = (_Float16)acc[nb][r];
    }
}

// ---------------------------------------------------------------------------
// Merge: out[g][dv] = sum_s O_s[g][dv] / sum_s l_s[g].
// ---------------------------------------------------------------------------
__global__ void merge_kernel(const _Float16* __restrict__ Opart,
                             const float* __restrict__ Lst,
                             float* __restrict__ out, int nsp) {
  int tid = blockIdx.x * blockDim.x + threadIdx.x;
  int g = tid >> 4;
  int d0 = (tid & 15) * 8;
  float den = 0.f;
  float num[8] = {0.f, 0.f, 0.f, 0.f, 0.f, 0.f, 0.f, 0.f};
  for (int s = 0; s < nsp; ++s) {
    den += Lst[(size_t)s * N_Q + g];
    half8 o = *(const half8*)(Opart + ((size_t)s * N_Q + g) * DHEAD + d0);
#pragma unroll
    for (int j = 0; j < 8; ++j) num[j] += (float)o[j];
  }
  float inv = 1.0f / den;
  floatx4 r0 = (floatx4){num[0] * inv, num[1] * inv, num[2] * inv, num[3] * inv};
  floatx4 r1 = (floatx4){num[4] * inv, num[5] * inv, num[6] * inv, num[7] * inv};
  float* dst = out + (size_t)g * DHEAD + d0;
  *(floatx4*)dst = r0;
  *(floatx4*)(dst + 4) = r1;
}

// ---------------------------------------------------------------------------
extern "C" void kernel_launch(void* const* d_in, const int* in_sizes, int n_in,
                              void* d_out, int out_size, void* d_ws,
                              size_t ws_size, hipStream_t stream) {
  const float* Q = (const float*)d_in[0];
  const float* K = (const float*)d_in[1];
  const float* V = (const float*)d_in[2];
  float* out = (float*)d_out;

  // ws layout: Kbc 2MiB | Vtc 2MiB | Opart fp16 nsp*2MiB | Lst nsp*32KiB
  const size_t need16 = (4ull << 20) + 16ull * N_Q * DHEAD * 2 + 16ull * N_Q * 4;
  const int nsp = (ws_size >= need16) ? 16 : 8;

  char* ws = (char*)d_ws;
  unsigned short* Kbc = (unsigned short*)(ws);
  unsigned short* Vtc = (unsigned short*)(ws + (2u << 20));
  _Float16* Opart = (_Float16*)(ws + (4u << 20));
  float* Lst = (float*)(ws + (4ull << 20) + (size_t)nsp * N_Q * DHEAD * 2);

  cvt_kernel<<<dim3(1536), dim3(256), 0, stream>>>(K, V, Kbc, Vtc);
  attn_kernel<<<dim3(N_Q / 128, nsp), dim3(256), 0, stream>>>(Q, Kbc, Vtc,
                                                              Opart, Lst);
  merge_kernel<<<dim3(512), dim3(256), 0, stream>>>(Opart, Lst, out, nsp);
}